// Round 10
// baseline (193.518 us; speedup 1.0000x reference)
//
#include <hip/hip_runtime.h>
#include <hip/hip_cooperative_groups.h>

namespace cg = cooperative_groups;

// Problem constants (match reference)
#define XD 256
#define YD 256
#define ZD 16
#define TD 5
#define BD 2
#define NP 300000
#define CMID 8
#define VPB (XD * YD * ZD * TD)        // 5,242,880 voxels per batch
#define NVOX (BD * VPB)                // 10,485,760 total voxels
#define MAXPTS (BD * NP)               // 600,000
// Occupancy layout: 8 bits per (b,x,y,z) cell (t occupies bits 0..4).
// idx8 = (b<<23)|(x<<15)|(y<<7)|(z<<3)|t  -> all power-of-2 decode.
#define OCC_BYTES (BD * XD * YD * ZD)  // 2 MiB (L2/L3-resident)
#define OCC_U128  (OCC_BYTES / 16)     // 131,072 16B columns
#define OUT_F4    (NVOX / 4)           // 2,621,440 float4

#define NBLK  512                      // coop grid: far under co-residency cap
#define NTHR  256
#define GSZ   (NBLK * NTHR)            // 131,072 threads
#define NSTRIP 2048                    // (b, x, y-quarter) strips
#define SCAT_BLOCKS ((MAXPTS + 255) / 256)   // 2344

// ---------------------------------------------------------------------------
// Shared device helpers (used by both the cooperative and fallback paths)
// ---------------------------------------------------------------------------
__device__ __forceinline__ void build_tab(
    const float* __restrict__ W0, const float* __restrict__ b0,
    const float* __restrict__ W1, const float* __restrict__ b1,
    float* tab, float* b0s, float* w1s, float* b1s) {
    int tid = threadIdx.x;
    // tab entry e = kb[0,27) * 8 + m[0,8): sum over set bits of m (dt order)
    // of W0 rows; rows padded to 12 floats.
    if (tid < 216) {
        int kb = tid >> 3;
        int m  = tid & 7;
        float acc[CMID];
#pragma unroll
        for (int c = 0; c < CMID; ++c) acc[c] = 0.0f;
#pragma unroll
        for (int dti = 0; dti < 3; ++dti) {
            if ((m >> dti) & 1) {
                const float* w = &W0[(kb * 3 + dti) * CMID];
#pragma unroll
                for (int c = 0; c < CMID; ++c) acc[c] += w[c];
            }
        }
#pragma unroll
        for (int c = 0; c < CMID; ++c) tab[tid * 12 + c] = acc[c];
    }
    if (tid < CMID) {
        b0s[tid] = b0[tid];
        w1s[tid] = W1[tid];
    }
    if (tid == 0) *b1s = b1[0];
}

// Strip-local conv: block handles columns (b, x, ny0..ny0+63). Thread owns
// (column cl = tid>>2, z-quarter zq = tid&3); neighbor columns captured into
// registers; per set bit of its own u32 word, compute 27-tap m-table conv.
__device__ __forceinline__ void do_strip(
    int s, const ulonglong2* __restrict__ occ128,
    const float* tab, const float* b0s, const float* w1s, const float* b1p,
    ulonglong2 (*cols)[66], float* __restrict__ out) {
    int tid = threadIdx.x;
    int b   = s >> 10;
    int x   = (s >> 2) & 255;
    int ny0 = (s & 3) << 6;

    // coalesced load of the 3x66 column neighborhood into LDS
    for (int j = tid; j < 3 * 66; j += NTHR) {
        int r   = j / 66;           // dxi
        int cyl = j % 66;           // local ny + 1
        int nx  = x + r - 1;
        int cy  = ny0 + cyl - 1;
        bool valid = ((unsigned)nx < XD) && ((unsigned)cy < YD);
        ulonglong2 col = occ128[(b << 16) | ((nx & 255) << 8) | (cy & 255)];
        ulonglong2 v;
        v.x = valid ? col.x : 0ull;
        v.y = valid ? col.y : 0ull;
        cols[r][cyl] = v;
    }
    __syncthreads();

    // capture 3x3 neighborhood into registers (4 lanes/addr broadcast)
    int cl = tid >> 2;
    int zq = tid & 3;
    ulonglong2 cr[3][3];
#pragma unroll
    for (int dxi = 0; dxi < 3; ++dxi)
#pragma unroll
        for (int dyi = 0; dyi < 3; ++dyi)
            cr[dxi][dyi] = cols[dxi][cl + dyi];
    float b1v = *b1p;
    __syncthreads();   // cols consumed; next strip may overwrite

    // own u32 word: z = zq*4 + (bi>>3), t = bi&7 (t bits 0..4 only)
    unsigned long long hw = (zq & 2) ? cr[1][1].y : cr[1][1].x;
    unsigned w = (unsigned)((zq & 1) ? (hw >> 32) : hw);

    while (w) {
        int bi = __ffs(w) - 1;
        w &= w - 1;
        int z = (zq << 2) + (bi >> 3);
        int t = bi & 7;

        float4 h0 = {0.f, 0.f, 0.f, 0.f};
        float4 h1 = {0.f, 0.f, 0.f, 0.f};
#pragma unroll
        for (int dxi = 0; dxi < 3; ++dxi) {
#pragma unroll
            for (int dyi = 0; dyi < 3; ++dyi) {
                ulonglong2 col = cr[dxi][dyi];       // registers, not LDS
                int p3 = (dxi * 3 + dyi) * 3;
#pragma unroll
                for (int dzi = 0; dzi < 3; ++dzi) {
                    int nz = z + dzi - 1;                     // [-1, 16]
                    unsigned sh = ((unsigned)nz * 8u) & 63u;  // wrap-safe
                    unsigned r = (unsigned)(((nz & 8) ? (col.y >> sh)
                                                      : (col.x >> sh)) & 0xffull);
                    r = ((unsigned)nz < ZD) ? r : 0u;
                    unsigned m = ((r << 1) >> t) & 7u;  // bits t-1,t,t+1
                    if (m) {                            // ~16% of taps fire
                        const float4* row =
                            (const float4*)&tab[((p3 + dzi) * 8 + (int)m) * 12];
                        h0 += row[0];
                        h1 += row[1];
                    }
                }
            }
        }

        float hc[CMID] = {h0.x, h0.y, h0.z, h0.w, h1.x, h1.y, h1.z, h1.w};
        float o = 0.0f;
#pragma unroll
        for (int c = 0; c < CMID; ++c) {
            float v = 0.5f * hc[c] + b0s[c];   // grid value is exactly 0.5
            v = v > 0.0f ? v : 0.0f;           // relu
            o += v * w1s[c];
        }
        out[(((x * YD + (ny0 + cl)) * ZD + z) * TD + t) + b * VPB] = o + b1v;
    }
}

__device__ __forceinline__ void scatter_point(
    const float4* __restrict__ pts, unsigned int* __restrict__ occ, int i) {
    float4 p = pts[i];
    // Match JAX exactly: floor(p / quant) (fp32 division), then clip.
    int cx = min(max((int)floorf(p.x / 0.4f), 0), XD - 1);
    int cy = min(max((int)floorf(p.y / 0.4f), 0), YD - 1);
    int cz = min(max((int)floorf(p.z / 0.4f), 0), ZD - 1);
    int ct = min(max((int)floorf(p.w / 1.0f), 0), TD - 1);
    int b  = i / NP;
    unsigned idx8 = ((unsigned)b << 23) | ((unsigned)cx << 15) |
                    ((unsigned)cy << 7) | ((unsigned)cz << 3) | (unsigned)ct;
    atomicOr(&occ[idx8 >> 5], 1u << (idx8 & 31));   // idempotent
}

// ---------------------------------------------------------------------------
// PRIMARY: single cooperative kernel, 2 grid.sync()s replace 2 kernel
// boundaries. 512 blocks, ~14 KB LDS -> co-residency easily satisfied.
// ---------------------------------------------------------------------------
__global__ __launch_bounds__(256) void fused_kernel(
    const float4* __restrict__ pts, unsigned int* __restrict__ occ,
    const float* __restrict__ W0, const float* __restrict__ b0,
    const float* __restrict__ W1, const float* __restrict__ b1,
    float* __restrict__ out) {
    __shared__ float tab[216 * 12];
    __shared__ ulonglong2 cols[3][66];
    __shared__ float b0s[CMID];
    __shared__ float w1s[CMID];
    __shared__ float b1s;

    cg::grid_group grid = cg::this_grid();
    int tid = threadIdx.x;
    int gid = blockIdx.x * NTHR + tid;

    // Phase A: mask table + zero occupancy bitfield
    build_tab(W0, b0, W1, b1, tab, b0s, w1s, &b1s);
    {
        uint4 z = {0u, 0u, 0u, 0u};
        for (int j = gid; j < OCC_U128; j += GSZ) ((uint4*)occ)[j] = z;
    }
    grid.sync();

    // Phase B: scatter points; zero dense output
    for (int i = gid; i < MAXPTS; i += GSZ) scatter_point(pts, occ, i);
    {
        float4 zf = {0.f, 0.f, 0.f, 0.f};
        float4* out4 = (float4*)out;
        for (int j = gid; j < OUT_F4; j += GSZ) out4[j] = zf;
    }
    grid.sync();

    // Phase C: strip-local conv (4 strips per block)
    const ulonglong2* occ128 = (const ulonglong2*)occ;
    for (int s = blockIdx.x; s < NSTRIP; s += NBLK)
        do_strip(s, occ128, tab, b0s, w1s, &b1s, cols, out);
}

// ---------------------------------------------------------------------------
// FALLBACK path (if cooperative launch is rejected): 3 ordinary kernels.
// ---------------------------------------------------------------------------
__global__ __launch_bounds__(256) void zero_kernel(
    uint4* __restrict__ occ, float4* __restrict__ out4) {
    int i = blockIdx.x * 256 + threadIdx.x;
    uint4 zu = {0u, 0u, 0u, 0u};
    for (int j = i; j < OCC_U128; j += 2048 * 256) occ[j] = zu;
    float4 zf = {0.f, 0.f, 0.f, 0.f};
    for (int j = i; j < OUT_F4; j += 2048 * 256) out4[j] = zf;
}

__global__ __launch_bounds__(256) void scatter_kernel(
    const float4* __restrict__ pts, unsigned int* __restrict__ occ) {
    int i = blockIdx.x * 256 + threadIdx.x;
    if (i < MAXPTS) scatter_point(pts, occ, i);
}

__global__ __launch_bounds__(256) void conv_kernel(
    const ulonglong2* __restrict__ occ128,
    const float* __restrict__ W0, const float* __restrict__ b0,
    const float* __restrict__ W1, const float* __restrict__ b1,
    float* __restrict__ out) {
    __shared__ float tab[216 * 12];
    __shared__ ulonglong2 cols[3][66];
    __shared__ float b0s[CMID];
    __shared__ float w1s[CMID];
    __shared__ float b1s;
    build_tab(W0, b0, W1, b1, tab, b0s, w1s, &b1s);
    // do_strip's internal __syncthreads orders tab build vs. tab reads
    do_strip(blockIdx.x, occ128, tab, b0s, w1s, &b1s, cols, out);
}

extern "C" void kernel_launch(void* const* d_in, const int* in_sizes, int n_in,
                              void* d_out, int out_size, void* d_ws, size_t ws_size,
                              hipStream_t stream) {
    const float4* pts = (const float4*)d_in[0];
    const float* W0   = (const float*)d_in[1];
    const float* b0   = (const float*)d_in[2];
    const float* W1   = (const float*)d_in[3];
    const float* b1   = (const float*)d_in[4];
    float* out = (float*)d_out;
    unsigned int* occ = (unsigned int*)d_ws;   // 2 MiB bitfield

    void* args[] = {(void*)&pts, (void*)&occ, (void*)&W0, (void*)&b0,
                    (void*)&W1, (void*)&b1, (void*)&out};
    hipError_t e = hipLaunchCooperativeKernel((void*)fused_kernel, dim3(NBLK),
                                              dim3(NTHR), args, 0, stream);
    if (e != hipSuccess) {
        // Cooperative launch rejected: equivalent 3-kernel path.
        zero_kernel<<<2048, 256, 0, stream>>>((uint4*)occ, (float4*)out);
        scatter_kernel<<<SCAT_BLOCKS, 256, 0, stream>>>(pts, occ);
        conv_kernel<<<NSTRIP, 256, 0, stream>>>(
            (const ulonglong2*)occ, W0, b0, W1, b1, out);
    }
}

// Round 11
// 66.899 us; speedup vs baseline: 2.8927x; 2.8927x over previous
//
#include <hip/hip_runtime.h>

// Problem constants (match reference)
#define XD 256
#define YD 256
#define ZD 16
#define TD 5
#define BD 2
#define NP 300000
#define CMID 8
#define VPB (XD * YD * ZD * TD)        // 5,242,880 voxels per batch
#define NVOX (BD * VPB)                // 10,485,760 total voxels
#define MAXPTS (BD * NP)               // 600,000
#define OUT_F4 (NVOX / 4)              // 2,621,440 float4

// Byte-per-voxel occupancy grid, t padded 5->8:
//   occ8[(colidx << 7) | (z << 3) | t], colidx = (b<<16)|(x<<8)|y
// 16 MiB total; scatter uses PLAIN byte stores (no atomics; dup races write
// the same value 1 -> deterministic). Kernel boundary flushes L2 -> coherent.
#define OCC8_BYTES (BD * XD * YD * ZD * 8)   // 16,777,216
#define OCC8_U128  (OCC8_BYTES / 16)         // 1,048,576
#define ZTOT_U128  (OCC8_U128 + OUT_F4)      // zero both in one kernel

#define SCAT_BLOCKS ((MAXPTS + 255) / 256)   // 2344
#define CONV_BLOCKS 2048                     // (b, x, y-quarter) strips

// ---------------------------------------------------------------------------
// Kernel 0: zero byte-grid + dense output with wide stores (58.7 MB).
// ---------------------------------------------------------------------------
__global__ __launch_bounds__(256) void zero_kernel(
    uint4* __restrict__ occ, uint4* __restrict__ out) {
    int i = blockIdx.x * 256 + threadIdx.x;
    uint4 z = {0u, 0u, 0u, 0u};
    for (int j = i; j < OCC8_U128; j += 2048 * 256) occ[j] = z;
    for (int j = i; j < OUT_F4; j += 2048 * 256) out[j] = z;
}

// ---------------------------------------------------------------------------
// Kernel 1: scatter points -> occupancy bytes (plain stores, NO atomics).
// ---------------------------------------------------------------------------
__global__ __launch_bounds__(256) void scatter_kernel(
    const float4* __restrict__ pts, unsigned char* __restrict__ occ8) {
    int i = blockIdx.x * 256 + threadIdx.x;
    if (i >= MAXPTS) return;
    float4 p = pts[i];
    // Match JAX exactly: floor(p / quant) (fp32 division), then clip.
    int cx = min(max((int)floorf(p.x / 0.4f), 0), XD - 1);
    int cy = min(max((int)floorf(p.y / 0.4f), 0), YD - 1);
    int cz = min(max((int)floorf(p.z / 0.4f), 0), ZD - 1);
    int ct = min(max((int)floorf(p.w / 1.0f), 0), TD - 1);
    int b  = i / NP;
    unsigned a = (((unsigned)b << 23) | ((unsigned)cx << 15) |
                  ((unsigned)cy << 7) | ((unsigned)cz << 3) | (unsigned)ct);
    occ8[a] = 1;   // fire-and-forget; duplicates write identical value
}

// LSB-gather: u64 of 8 bytes (each 0 or 1) -> 8-bit mask (byte j -> bit j).
// Shift-or cascade {0,7,14,21,28,35,42,49}; no spurious bits in [0,8).
__device__ __forceinline__ unsigned pack8(unsigned long long v) {
    v |= v >> 7;
    v |= v >> 14;
    v |= v >> 28;
    return (unsigned)v & 0xffu;
}

// ---------------------------------------------------------------------------
// Kernel 2: strip-local conv. Block owns columns (b, x, ny0..ny0+63):
//   1. coalesced byte-grid load of 3x66 neighbor columns (128 B each),
//      in-register byte->bit repack, packed 16 B/column into LDS
//   2. thread (cl=tid>>2, zq=tid&3) captures its 3x3 columns into registers
//   3. per set bit of its own u32 word: 27-tap m-table conv + ReLU + proj
// ---------------------------------------------------------------------------
__global__ __launch_bounds__(256) void conv_kernel(
    const ulonglong2* __restrict__ occ16,   // byte grid as 16B (z-pair) units
    const float* __restrict__ W0,   // (81, 1, 8)
    const float* __restrict__ b0,   // (8)
    const float* __restrict__ W1,   // (8, 1)
    const float* __restrict__ b1,   // (1)
    float* __restrict__ out) {
    __shared__ float tab[216 * 12];         // 10.4 KB mask table
    __shared__ ulonglong2 pcols[3 * 66];    // 3.2 KB packed columns
    __shared__ float b0s[CMID];
    __shared__ float w1s[CMID];
    __shared__ float b1s;

    int tid = threadIdx.x;
    int s   = blockIdx.x;
    int b   = s >> 10;
    int x   = (s >> 2) & 255;
    int ny0 = (s & 3) << 6;

    // --- mask table: entry e = kb[0,27)*8 + m[0,8); rows padded to 12 ---
    if (tid < 216) {
        int kb = tid >> 3;
        int m  = tid & 7;
        float acc[CMID];
#pragma unroll
        for (int c = 0; c < CMID; ++c) acc[c] = 0.0f;
#pragma unroll
        for (int dti = 0; dti < 3; ++dti) {
            if ((m >> dti) & 1) {
                const float* w = &W0[(kb * 3 + dti) * CMID];
#pragma unroll
                for (int c = 0; c < CMID; ++c) acc[c] += w[c];
            }
        }
#pragma unroll
        for (int c = 0; c < CMID; ++c) tab[tid * 12 + c] = acc[c];
    }
    if (tid < CMID) {
        b0s[tid] = b0[tid];
        w1s[tid] = W1[tid];
    }
    if (tid == 0) b1s = b1[0];

    // --- load byte-grid neighborhood + repack to bits ---
    // task j = (col cj in [0,198)) * 8 + z-pair zp in [0,8): 16 B -> u16
    for (int j = tid; j < 198 * 8; j += 256) {
        int cj  = j >> 3;
        int zp  = j & 7;
        int r   = cj / 66;          // dxi
        int cyl = cj % 66;          // local ny + 1
        int nx  = x + r - 1;
        int cy  = ny0 + cyl - 1;
        bool valid = ((unsigned)nx < XD) && ((unsigned)cy < YD);
        int colidx = (b << 16) | ((nx & 255) << 8) | (cy & 255);
        ulonglong2 v = occ16[(colidx << 3) + zp];   // 16 bytes = z-slots 2zp, 2zp+1
        unsigned m0 = pack8(v.x);
        unsigned m1 = pack8(v.y);
        unsigned short pk = (unsigned short)(m0 | (m1 << 8));
        ((unsigned short*)pcols)[cj * 8 + zp] = valid ? pk : (unsigned short)0;
    }
    __syncthreads();

    // --- capture 3x3 packed columns into registers (4 lanes/addr bcast) ---
    int cl = tid >> 2;
    int zq = tid & 3;
    ulonglong2 cr[3][3];
#pragma unroll
    for (int dxi = 0; dxi < 3; ++dxi)
#pragma unroll
        for (int dyi = 0; dyi < 3; ++dyi)
            cr[dxi][dyi] = pcols[dxi * 66 + cl + dyi];

    // own u32 word: z in [zq*4, zq*4+4), byte z -> bit t
    unsigned long long hw = (zq & 2) ? cr[1][1].y : cr[1][1].x;
    unsigned w = (unsigned)((zq & 1) ? (hw >> 32) : hw);

    while (w) {
        int bi = __ffs(w) - 1;
        w &= w - 1;
        int z = (zq << 2) + (bi >> 3);
        int t = bi & 7;

        float4 h0 = {0.f, 0.f, 0.f, 0.f};
        float4 h1 = {0.f, 0.f, 0.f, 0.f};
#pragma unroll
        for (int dxi = 0; dxi < 3; ++dxi) {
#pragma unroll
            for (int dyi = 0; dyi < 3; ++dyi) {
                ulonglong2 col = cr[dxi][dyi];       // registers, not LDS
                int p3 = (dxi * 3 + dyi) * 3;
#pragma unroll
                for (int dzi = 0; dzi < 3; ++dzi) {
                    int nz = z + dzi - 1;                     // [-1, 16]
                    unsigned sh = ((unsigned)nz * 8u) & 63u;  // wrap-safe
                    unsigned r = (unsigned)(((nz & 8) ? (col.y >> sh)
                                                      : (col.x >> sh)) & 0xffull);
                    r = ((unsigned)nz < ZD) ? r : 0u;
                    unsigned m = ((r << 1) >> t) & 7u;  // bits t-1,t,t+1
                    if (m) {                            // ~16% of taps fire
                        const float4* row =
                            (const float4*)&tab[((p3 + dzi) * 8 + (int)m) * 12];
                        h0 += row[0];
                        h1 += row[1];
                    }
                }
            }
        }

        float hc[CMID] = {h0.x, h0.y, h0.z, h0.w, h1.x, h1.y, h1.z, h1.w};
        float o = 0.0f;
#pragma unroll
        for (int c = 0; c < CMID; ++c) {
            float v = 0.5f * hc[c] + b0s[c];   // grid value is exactly 0.5
            v = v > 0.0f ? v : 0.0f;           // relu
            o += v * w1s[c];
        }
        out[(((x * YD + (ny0 + cl)) * ZD + z) * TD + t) + b * VPB] = o + b1s;
    }
}

extern "C" void kernel_launch(void* const* d_in, const int* in_sizes, int n_in,
                              void* d_out, int out_size, void* d_ws, size_t ws_size,
                              hipStream_t stream) {
    const float4* pts = (const float4*)d_in[0];
    const float* W0   = (const float*)d_in[1];
    const float* b0   = (const float*)d_in[2];
    const float* W1   = (const float*)d_in[3];
    const float* b1   = (const float*)d_in[4];
    float* out = (float*)d_out;
    unsigned char* occ8 = (unsigned char*)d_ws;   // 16 MiB byte grid

    zero_kernel<<<2048, 256, 0, stream>>>((uint4*)occ8, (uint4*)out);
    scatter_kernel<<<SCAT_BLOCKS, 256, 0, stream>>>(pts, occ8);
    conv_kernel<<<CONV_BLOCKS, 256, 0, stream>>>(
        (const ulonglong2*)occ8, W0, b0, W1, b1, out);
}